// Round 8
// baseline (404.221 us; speedup 1.0000x reference)
//
#include <hip/hip_runtime.h>
#include <cmath>

// ---------------------------------------------------------------------------
// MemoryBankV2: B=128, T=32, D=512, L=2.  Rows = B*T = 4096.
// Round 8: LDS-free fragment-major GEMMs.  All bf16 operands stored in
// MFMA-fragment-major layout (1KB chunk per 16row x 32k fragment, lane l
// owns bytes [l*16, l*16+16)).  Each wave = independent 64x64 output tile,
// loads fragments straight from L2 via coalesced global_load_dwordx4,
// no LDS, no barriers.  12 latency chains/CU vs 3 in the LDS design.
// ---------------------------------------------------------------------------

#define ROWS 4096
#define DIM  512

typedef __bf16 bf16x8 __attribute__((ext_vector_type(8)));
typedef float  f32x4  __attribute__((ext_vector_type(4)));
typedef unsigned short u16;
typedef u16 u16x4 __attribute__((ext_vector_type(4)));
typedef u16 u16x8 __attribute__((ext_vector_type(8)));

#define RD ((size_t)ROWS * DIM)

__device__ __forceinline__ u16 f2bf(float x) {
    union { float f; unsigned u; } c; c.f = x;
    const unsigned r = (c.u + 0x7FFFu + ((c.u >> 16) & 1u)) >> 16;
    return (u16)r;
}

__device__ __forceinline__ float gelu_f(float v) {
    return 0.5f * v * (1.0f + erff(v * 0.70710678118654752f));
}

// fragment-major address (u16 units) for element block (r, k..k+7), k%8==0,
// in a matrix [R][K]: chunk = (r>>4)*(K>>5) + (k>>5); lane = (r&15)|(((k>>3)&3)<<4)
__device__ __forceinline__ size_t fragAddr(int r, int k, int K) {
    return ((size_t)((r >> 4) * (K >> 5) + (k >> 5)) << 9)
         + (((r & 15) | (((k >> 3) & 3) << 4)) << 3);
}

// ---------------- wave GEMM: one wave computes a 64x64 tile -----------------
// C[M,N] = epi(A[M,K] @ B[N,K]^T); A,B fragment-major bf16; kt in 32-k units.
// EPI: 0: f32 row-major = acc*scale | 2: bf16 frag-major = acc+bias
//      3: bf16 frag-major = gelu(acc+bias) | 4: bf16 frag-major TRANSPOSED
//         (output matrix [N rows][M as K], for vT)
template<int EPI>
__device__ __forceinline__ void wgemm(
    const u16* __restrict__ A, int KA,
    const u16* __restrict__ B,
    const float* __restrict__ bias,
    void* __restrict__ C, int ldcK,
    int ktBeg, int ktEnd, float scale, int mt, int nt)
{
    const int lane = threadIdx.x & 63;
    const int l15 = lane & 15, lq = lane >> 4;

    f32x4 acc[4][4];
    #pragma unroll
    for (int i = 0; i < 4; ++i)
        #pragma unroll
        for (int j = 0; j < 4; ++j)
            acc[i][j] = (f32x4){0.f, 0.f, 0.f, 0.f};

    const int ka5 = KA >> 5;
    const u16* pa[4]; const u16* pb[4];
    #pragma unroll
    for (int i = 0; i < 4; ++i)
        pa[i] = A + (((size_t)((mt * 4 + i) * ka5 + ktBeg)) << 9) + (lane << 3);
    #pragma unroll
    for (int j = 0; j < 4; ++j)
        pb[j] = B + (((size_t)((nt * 4 + j) * ka5 + ktBeg)) << 9) + (lane << 3);

    for (int kt = ktBeg; kt < ktEnd; ++kt) {
        bf16x8 a_[4], b_[4];
        #pragma unroll
        for (int i = 0; i < 4; ++i) {
            a_[i] = *reinterpret_cast<const bf16x8*>(pa[i]); pa[i] += 512;
        }
        #pragma unroll
        for (int j = 0; j < 4; ++j) {
            b_[j] = *reinterpret_cast<const bf16x8*>(pb[j]); pb[j] += 512;
        }
        #pragma unroll
        for (int i = 0; i < 4; ++i)
            #pragma unroll
            for (int j = 0; j < 4; ++j) {
                if constexpr (EPI == 4)   // unswapped: reg dim = M (token)
                    acc[i][j] = __builtin_amdgcn_mfma_f32_16x16x32_bf16(
                        a_[i], b_[j], acc[i][j], 0, 0, 0);
                else                      // swapped: reg dim = N
                    acc[i][j] = __builtin_amdgcn_mfma_f32_16x16x32_bf16(
                        b_[j], a_[i], acc[i][j], 0, 0, 0);
            }
    }

    if constexpr (EPI == 0) {
        // row-major f32, scaled.  D[n = lq*4+reg][m = l15] per frag (swapped).
        #pragma unroll
        for (int j = 0; j < 4; ++j) {
            const int col0 = nt * 64 + (j << 4) + (lq << 2);
            #pragma unroll
            for (int i = 0; i < 4; ++i) {
                const int row = mt * 64 + (i << 4) + l15;
                f32x4 v = acc[i][j];
                v[0] *= scale; v[1] *= scale; v[2] *= scale; v[3] *= scale;
                *reinterpret_cast<f32x4*>(&((float*)C)[(size_t)row * ldcK + col0]) = v;
            }
        }
    } else if constexpr (EPI == 2 || EPI == 3) {
        // bf16 frag-major out [M rows][ldcK], +bias (and gelu for 3)
        #pragma unroll
        for (int j = 0; j < 4; ++j) {
            const int co = (j << 4) + (lq << 2);          // col offset in tile
            const int col0 = nt * 64 + co;
            const float4 bj = *reinterpret_cast<const float4*>(&bias[col0]);
            const int ktO = (nt << 1) + (co >> 5);
            const int lnO = l15 | (((co >> 3) & 3) << 4);
            const int elem = co & 7;
            #pragma unroll
            for (int i = 0; i < 4; ++i) {
                const int rt = mt * 4 + i;
                f32x4 v = acc[i][j];
                v[0] += bj.x; v[1] += bj.y; v[2] += bj.z; v[3] += bj.w;
                if (EPI == 3) {
                    v[0] = gelu_f(v[0]); v[1] = gelu_f(v[1]);
                    v[2] = gelu_f(v[2]); v[3] = gelu_f(v[3]);
                }
                u16x4 pk = {f2bf(v[0]), f2bf(v[1]), f2bf(v[2]), f2bf(v[3])};
                u16* dst = (u16*)C + (((size_t)(rt * (ldcK >> 5) + ktO)) << 9)
                         + (lnO << 3) + elem;
                *reinterpret_cast<u16x4*>(dst) = pk;
            }
        }
    } else {
        // EPI4: vT frag-major [N=d rows][ldcK = token K], +bias.
        // unswapped: D[m = lq*4+reg (token)][n = l15 (d)].
        #pragma unroll
        for (int j = 0; j < 4; ++j) {
            const int rtO = nt * 4 + j;                   // d tile
            const int col = nt * 64 + (j << 4) + l15;     // d
            const float bj = bias[col];
            #pragma unroll
            for (int i = 0; i < 4; ++i) {
                const int ro = (i << 4) + (lq << 2);      // token offset in tile
                const int ktO = (mt << 1) + (ro >> 5);
                const int lnO = l15 | (((ro >> 3) & 3) << 4);
                const int elem = ro & 7;
                u16x4 pk;
                #pragma unroll
                for (int r = 0; r < 4; ++r) pk[r] = f2bf(acc[i][j][r] + bj);
                u16* dst = (u16*)C + (((size_t)(rtO * (ldcK >> 5) + ktO)) << 9)
                         + (lnO << 3) + elem;
                *reinterpret_cast<u16x4*>(dst) = pk;
            }
        }
    }
}

// ---------------- GEMM kernels (4 independent waves per block) --------------
__global__ __launch_bounds__(256, 3) void k_qkv(
    const u16* __restrict__ xa, const u16* __restrict__ cfb,
    const u16* __restrict__ Wqb, const u16* __restrict__ Wkb,
    const u16* __restrict__ Wvb,
    const float* __restrict__ bq, const float* __restrict__ bk,
    const float* __restrict__ bv,
    u16* __restrict__ q, u16* __restrict__ k, u16* __restrict__ vT)
{
    const int g = blockIdx.x * 4 + (threadIdx.x >> 6);   // 0..1535
    const int which = g >> 9;
    const int t = g & 511;
    const int mt = t >> 3, nt = t & 7;
    if (which == 0)
        wgemm<2>(xa, 512, Wqb, bq, q, 512, 0, 16, 1.f, mt, nt);
    else if (which == 1)
        wgemm<2>(cfb, 512, Wkb, bk, k, 512, 0, 16, 1.f, mt, nt);
    else
        wgemm<4>(cfb, 512, Wvb, bv, vT, 4096, 0, 16, 1.f, mt, nt);
}

// block-causal scores: 64x64 tiles, live iff nt <= mt; 2080 waves.
__global__ __launch_bounds__(256, 3) void k_tri(
    const u16* __restrict__ qb, const u16* __restrict__ kb,
    float* __restrict__ S, float scale)
{
    const int z = blockIdx.x * 4 + (threadIdx.x >> 6);   // 0..2079
    int mt = (int)((sqrtf((float)(8 * z + 1)) - 1.0f) * 0.5f);
    while ((mt + 1) * (mt + 2) / 2 <= z) ++mt;
    while (mt * (mt + 1) / 2 > z) --mt;
    const int nt = z - mt * (mt + 1) / 2;
    wgemm<0>(qb, 512, kb, nullptr, S, 4096, 0, 16, scale, mt, nt);
}

// AV split-K: partials[z] = P[64mt.., kt chunk] @ vT^T; kt bound = 2mt+1.
__global__ __launch_bounds__(256, 3) void k_av(
    const u16* __restrict__ P, const u16* __restrict__ vT,
    float* __restrict__ part)
{
    const int g = blockIdx.x * 4 + (threadIdx.x >> 6);   // 0..2047
    const int z = g & 3, nt = (g >> 2) & 7, mt = g >> 5;
    const int kts = 2 * mt + 1;
    const int ch = (kts + 3) >> 2;
    int kb = z * ch; if (kb > kts) kb = kts;
    int ke = kb + ch; if (ke > kts) ke = kts;
    wgemm<0>(P, 4096, vT, nullptr, part + (size_t)z * RD, 512, kb, ke, 1.f, mt, nt);
}

__global__ __launch_bounds__(256, 3) void k_mlp1(
    const u16* __restrict__ xb, const u16* __restrict__ W1b,
    const float* __restrict__ b1, u16* __restrict__ h)
{
    const int g = blockIdx.x * 4 + (threadIdx.x >> 6);   // 0..2047
    const int mt = g >> 5, nt = g & 31;
    wgemm<3>(xb, 512, W1b, b1, h, 2048, 0, 16, 1.f, mt, nt);
}

__global__ __launch_bounds__(256, 3) void k_mlp2(
    const u16* __restrict__ h, const u16* __restrict__ W2b,
    float* __restrict__ part)
{
    const int g = blockIdx.x * 4 + (threadIdx.x >> 6);   // 0..2047
    const int z = g & 3, nt = (g >> 2) & 7, mt = g >> 5;
    wgemm<0>(h, 2048, W2b, nullptr, part + (size_t)z * RD, 512,
             z * 16, z * 16 + 16, 1.f, mt, nt);
}

__global__ __launch_bounds__(256, 3) void k_gate(
    const u16* __restrict__ cat, const u16* __restrict__ Wsb,
    float* __restrict__ part)
{
    const int g = blockIdx.x * 4 + (threadIdx.x >> 6);   // 0..1023
    const int z = g & 1, nt = (g >> 1) & 7, mt = g >> 4;
    wgemm<0>(cat, 1024, Wsb, nullptr, part + (size_t)z * RD, 512,
             z * 16, z * 16 + 16, 1.f, mt, nt);
}

// ------- masked row softmax (2 passes): p = exp(s - max) bf16 FRAG-MAJOR,
//         UNNORMALIZED; sums[row] = denom.  Zero-pads to the 64-tile bound.
__global__ __launch_bounds__(256) void softmax_pbf(
    const float* __restrict__ S, u16* __restrict__ P, float* __restrict__ sums)
{
    const int row = blockIdx.x;
    const int b   = row >> 5;
    const int Lb  = b << 5;
    const int bound = ((row >> 6) << 6) + 32;   // kt bound for this 64-row tile
    const float* s = S + (size_t)row * 4096;
    const int tid = threadIdx.x;

    const u16x8 z8 = {0, 0, 0, 0, 0, 0, 0, 0};
    for (int m = Lb + tid * 8; m < bound; m += 2048)
        *reinterpret_cast<u16x8*>(&P[fragAddr(row, m, 4096)]) = z8;
    if (b == 0) { if (tid == 0) sums[row] = 1.f; return; }

    __shared__ float red[4];
    float mx = -3.0e38f;
    for (int m = tid * 4; m < Lb; m += 1024) {
        const float4 v = *reinterpret_cast<const float4*>(&s[m]);
        mx = fmaxf(mx, fmaxf(fmaxf(v.x, v.y), fmaxf(v.z, v.w)));
    }
    #pragma unroll
    for (int off = 32; off; off >>= 1) mx = fmaxf(mx, __shfl_xor(mx, off));
    if ((tid & 63) == 0) red[tid >> 6] = mx;
    __syncthreads();
    mx = fmaxf(fmaxf(red[0], red[1]), fmaxf(red[2], red[3]));
    __syncthreads();

    float sum = 0.f;
    for (int m = tid * 8; m < Lb; m += 2048) {
        const float4 v0 = *reinterpret_cast<const float4*>(&s[m]);
        const float4 v1 = *reinterpret_cast<const float4*>(&s[m + 4]);
        float e[8];
        e[0] = expf(v0.x - mx); e[1] = expf(v0.y - mx);
        e[2] = expf(v0.z - mx); e[3] = expf(v0.w - mx);
        e[4] = expf(v1.x - mx); e[5] = expf(v1.y - mx);
        e[6] = expf(v1.z - mx); e[7] = expf(v1.w - mx);
        u16x8 o;
        #pragma unroll
        for (int i = 0; i < 8; ++i) { sum += e[i]; o[i] = f2bf(e[i]); }
        *reinterpret_cast<u16x8*>(&P[fragAddr(row, m, 4096)]) = o;
    }
    #pragma unroll
    for (int off = 32; off; off >>= 1) sum += __shfl_xor(sum, off);
    if ((tid & 63) == 0) red[tid >> 6] = sum;
    __syncthreads();
    if (tid == 0)
        sums[row] = fmaxf(red[0] + red[1] + red[2] + red[3], 1e-30f);
}

// --- x = LN(xin + (sum_s part[s]) * (DIV? 1/sums[row] : 1) (+bias)) ---------
// writes f32 row-major Xout and FRAG-MAJOR bf16 Xbf (K=512).
template<int NS, bool HASB, bool DIV>
__global__ __launch_bounds__(256) void ln_res_ps(
    const float* __restrict__ Xin, const float* __restrict__ part,
    const float* __restrict__ bias, const float* __restrict__ sums,
    const float* __restrict__ gamma, const float* __restrict__ beta,
    float* __restrict__ Xout, u16* __restrict__ Xbf)
{
    const int row  = blockIdx.x * 4 + (threadIdx.x >> 6);
    const int lane = threadIdx.x & 63;
    const float* xr = Xin + (size_t)row * DIM;
    const int d0 = lane << 3;
    const float inv = DIV ? (1.0f / sums[row]) : 1.0f;

    const float4 x0 = *reinterpret_cast<const float4*>(&xr[d0]);
    const float4 x1 = *reinterpret_cast<const float4*>(&xr[d0 + 4]);
    float a[8] = {0.f, 0.f, 0.f, 0.f, 0.f, 0.f, 0.f, 0.f};
    #pragma unroll
    for (int s = 0; s < NS; ++s) {
        const float* pr = part + (size_t)s * RD + (size_t)row * DIM + d0;
        const float4 p0 = *reinterpret_cast<const float4*>(pr);
        const float4 p1 = *reinterpret_cast<const float4*>(pr + 4);
        a[0] += p0.x; a[1] += p0.y; a[2] += p0.z; a[3] += p0.w;
        a[4] += p1.x; a[5] += p1.y; a[6] += p1.z; a[7] += p1.w;
    }
    float v[8] = {x0.x, x0.y, x0.z, x0.w, x1.x, x1.y, x1.z, x1.w};
    #pragma unroll
    for (int i = 0; i < 8; ++i) v[i] += a[i] * inv;
    if (HASB) {
        const float4 b0 = *reinterpret_cast<const float4*>(&bias[d0]);
        const float4 b1 = *reinterpret_cast<const float4*>(&bias[d0 + 4]);
        v[0] += b0.x; v[1] += b0.y; v[2] += b0.z; v[3] += b0.w;
        v[4] += b1.x; v[5] += b1.y; v[6] += b1.z; v[7] += b1.w;
    }

    float sm = 0.f;
    #pragma unroll
    for (int i = 0; i < 8; ++i) sm += v[i];
    #pragma unroll
    for (int off = 32; off; off >>= 1) sm += __shfl_xor(sm, off);
    const float mu = sm * (1.0f / 512.0f);

    float qs = 0.f;
    #pragma unroll
    for (int i = 0; i < 8; ++i) { const float d = v[i] - mu; qs += d * d; }
    #pragma unroll
    for (int off = 32; off; off >>= 1) qs += __shfl_xor(qs, off);
    const float rs = rsqrtf(qs * (1.0f / 512.0f) + 1e-5f);

    const float4 g0 = *reinterpret_cast<const float4*>(&gamma[d0]);
    const float4 g1 = *reinterpret_cast<const float4*>(&gamma[d0 + 4]);
    const float4 b0 = *reinterpret_cast<const float4*>(&beta[d0]);
    const float4 b1 = *reinterpret_cast<const float4*>(&beta[d0 + 4]);
    float o[8];
    o[0] = (v[0] - mu) * rs * g0.x + b0.x;
    o[1] = (v[1] - mu) * rs * g0.y + b0.y;
    o[2] = (v[2] - mu) * rs * g0.z + b0.z;
    o[3] = (v[3] - mu) * rs * g0.w + b0.w;
    o[4] = (v[4] - mu) * rs * g1.x + b1.x;
    o[5] = (v[5] - mu) * rs * g1.y + b1.y;
    o[6] = (v[6] - mu) * rs * g1.z + b1.z;
    o[7] = (v[7] - mu) * rs * g1.w + b1.w;

    float4 f0 = {o[0], o[1], o[2], o[3]}, f1 = {o[4], o[5], o[6], o[7]};
    *reinterpret_cast<float4*>(&Xout[(size_t)row * DIM + d0])     = f0;
    *reinterpret_cast<float4*>(&Xout[(size_t)row * DIM + d0 + 4]) = f1;
    u16x8 ob;
    #pragma unroll
    for (int i = 0; i < 8; ++i) ob[i] = f2bf(o[i]);
    *reinterpret_cast<u16x8*>(&Xbf[fragAddr(row, d0, 512)]) = ob;
}

// ---------------- f32 row-major -> bf16 FRAG-MAJOR conversion ---------------
// coalesced-write form: thread owns output lane-slot s = (blk-start)*256+tid.
struct ConvArgs {
    const float* src[7];
    u16* dst[7];
    int start[8];      // block prefix
    int K[7];          // inner dim of each matrix
};

__global__ __launch_bounds__(256) void conv_all(ConvArgs a)
{
    const int b = blockIdx.x;
    int seg = 0;
    #pragma unroll
    for (int i = 1; i < 7; ++i) seg += (a.start[i] <= b) ? 1 : 0;
    const int s = (b - a.start[seg]) * 256 + threadIdx.x;  // lane-slot id
    const int K = a.K[seg];
    const int fc = s >> 6, lane = s & 63;
    const int rt = fc / (K >> 5), kt = fc % (K >> 5);
    const int r = (rt << 4) + (lane & 15);
    const int k = (kt << 5) + ((lane >> 4) << 3);
    const float* src = a.src[seg] + (size_t)r * K + k;
    const float4 lo = *reinterpret_cast<const float4*>(src);
    const float4 hi = *reinterpret_cast<const float4*>(src + 4);
    u16x8 o = {f2bf(lo.x), f2bf(lo.y), f2bf(lo.z), f2bf(lo.w),
               f2bf(hi.x), f2bf(hi.y), f2bf(hi.z), f2bf(hi.w)};
    *reinterpret_cast<u16x8*>(&a.dst[seg][(size_t)s << 3]) = o;
}

// ---------------- small helpers ---------------------------------------------
// cat[row] = [cf[row], (row<32 ? cf : x)[row]], all frag-major.
__global__ __launch_bounds__(256) void build_cat(
    u16* __restrict__ cat, const u16* __restrict__ cfb, const u16* __restrict__ xbf)
{
    const int idx = blockIdx.x * 256 + threadIdx.x;
    const int row = idx >> 7;
    const int c0  = (idx & 127) << 3;
    u16x8 v;
    if (c0 < 512)
        v = *reinterpret_cast<const u16x8*>(&cfb[fragAddr(row, c0, 512)]);
    else {
        const u16* src2 = (row < 32) ? cfb : xbf;
        v = *reinterpret_cast<const u16x8*>(&src2[fragAddr(row, c0 - 512, 512)]);
    }
    *reinterpret_cast<u16x8*>(&cat[fragAddr(row, c0, 1024)]) = v;
}

__global__ __launch_bounds__(256) void final_gate_ps(
    float4* __restrict__ out, const float4* __restrict__ cf,
    const float4* __restrict__ x, const float* __restrict__ part,
    const float* __restrict__ bias)
{
    const int idx = blockIdx.x * 256 + threadIdx.x;
    const int row = idx >> 7;
    const int c4  = idx & 127;
    const float4 zc = cf[idx];
    const float4 p0 = reinterpret_cast<const float4*>(part)[idx];
    const float4 p1 = reinterpret_cast<const float4*>(part + RD)[idx];
    const float4 bb = *reinterpret_cast<const float4*>(&bias[c4 << 2]);
    const float4 za = (row < 32) ? zc : x[idx];
    float4 o;
    { const float g = 1.0f / (1.0f + expf(-(p0.x + p1.x + bb.x))); o.x = g * zc.x + (1.0f - g) * za.x; }
    { const float g = 1.0f / (1.0f + expf(-(p0.y + p1.y + bb.y))); o.y = g * zc.y + (1.0f - g) * za.y; }
    { const float g = 1.0f / (1.0f + expf(-(p0.z + p1.z + bb.z))); o.z = g * zc.z + (1.0f - g) * za.z; }
    { const float g = 1.0f / (1.0f + expf(-(p0.w + p1.w + bb.w))); o.w = g * zc.w + (1.0f - g) * za.w; }
    out[idx] = o;
}

// ---------------------------------------------------------------------------
extern "C" void kernel_launch(void* const* d_in, const int* in_sizes, int n_in,
                              void* d_out, int out_size, void* d_ws, size_t ws_size,
                              hipStream_t stream)
{
    const float* cf   = (const float*)d_in[0];
    const float* Wq   = (const float*)d_in[1];
    const float* bq   = (const float*)d_in[2];
    const float* Wk   = (const float*)d_in[3];
    const float* bk   = (const float*)d_in[4];
    const float* Wv   = (const float*)d_in[5];
    const float* bv   = (const float*)d_in[6];
    const float* ln1g = (const float*)d_in[7];
    const float* ln1b = (const float*)d_in[8];
    const float* W1   = (const float*)d_in[9];
    const float* b1   = (const float*)d_in[10];
    const float* W2   = (const float*)d_in[11];
    const float* b2   = (const float*)d_in[12];
    const float* ln2g = (const float*)d_in[13];
    const float* ln2b = (const float*)d_in[14];
    const float* Wsg  = (const float*)d_in[15];
    const float* bsg  = (const float*)d_in[16];
    float* out = (float*)d_out;

    float* ws   = (float*)d_ws;
    float* x    = ws;                               // [4096,512] f32 row-major
    float* sums = ws + RD;                          // [4096] f32
    float* s    = ws + 2 * RD;                      // [4096,4096] f32 (attn)
    float* part = ws + 2 * RD;                      // 4x[4096,512] f32 partials
                                                    // (aliases s; s dead then)
    u16*  pbf  = (u16*)(ws + 10 * RD);              // shared: p / h / cat (bf16)
    u16*  hbf  = pbf;
    u16*  catb = pbf;
    u16*  bfb  = (u16*)(ws + 14 * RD);
    u16* cfb = bfb;
    u16* xbf = bfb + RD;
    u16* qbf = bfb + 2 * RD;
    u16* kbf = bfb + 3 * RD;
    u16* vTb = bfb + 4 * RD;                        // frag [512][4096]
    u16* Wqb = bfb + 5 * RD;
    u16* Wkb = Wqb + 524288;
    u16* Wvb = Wkb + 524288;
    u16* W1b = Wvb + 524288;
    u16* W2b = W1b + 2097152;
    u16* Wsb = W2b + 2097152;

    const float scale = 0.044194173824159216f;      // 1/sqrt(512)

    ConvArgs ca;
    ca.src[0] = cf;  ca.dst[0] = cfb;  ca.K[0] = 512;
    ca.src[1] = Wq;  ca.dst[1] = Wqb;  ca.K[1] = 512;
    ca.src[2] = Wk;  ca.dst[2] = Wkb;  ca.K[2] = 512;
    ca.src[3] = Wv;  ca.dst[3] = Wvb;  ca.K[3] = 512;
    ca.src[4] = W1;  ca.dst[4] = W1b;  ca.K[4] = 512;
    ca.src[5] = W2;  ca.dst[5] = W2b;  ca.K[5] = 2048;
    ca.src[6] = Wsg; ca.dst[6] = Wsb;  ca.K[6] = 1024;
    ca.start[0] = 0;    ca.start[1] = 1024; ca.start[2] = 1280;
    ca.start[3] = 1536; ca.start[4] = 1792; ca.start[5] = 2816;
    ca.start[6] = 3840; ca.start[7] = 4096;
    conv_all<<<4096, 256, 0, stream>>>(ca);

    for (int l = 0; l < 2; ++l) {
        const u16* xa = (l == 0) ? cfb : xbf;
        k_qkv<<<384, 256, 0, stream>>>(
            xa, cfb, Wqb + l * 262144, Wkb + l * 262144, Wvb + l * 262144,
            bq + l * 512, bk + l * 512, bv + l * 512, qbf, kbf, vTb);
        k_tri<<<520, 256, 0, stream>>>(qbf, kbf, s, scale);
        softmax_pbf<<<4096, 256, 0, stream>>>(s, pbf, sums);
        k_av<<<512, 256, 0, stream>>>(pbf, vTb, part);
        ln_res_ps<4, false, true><<<1024, 256, 0, stream>>>(
            (l == 0) ? cf : x, part, nullptr, sums,
            ln1g + l * 512, ln1b + l * 512, x, xbf);
        k_mlp1<<<512, 256, 0, stream>>>(xbf, W1b + l * 1048576, b1 + l * 2048, hbf);
        k_mlp2<<<512, 256, 0, stream>>>(hbf, W2b + l * 1048576, part);
        ln_res_ps<4, true, false><<<1024, 256, 0, stream>>>(
            x, part, b2 + l * 512, nullptr,
            ln2g + l * 512, ln2b + l * 512, x, xbf);
    }

    build_cat<<<2048, 256, 0, stream>>>(catb, cfb, xbf);
    k_gate<<<256, 256, 0, stream>>>(catb, Wsb, part);
    final_gate_ps<<<2048, 256, 0, stream>>>((float4*)out, (const float4*)cf,
                                            (const float4*)x, part, bsg);
}

// Round 9
// 307.814 us; speedup vs baseline: 1.3132x; 1.3132x over previous
//
#include <hip/hip_runtime.h>
#include <cmath>

// ---------------------------------------------------------------------------
// MemoryBankV2: B=128, T=32, D=512, L=2.  Rows = B*T = 4096.
// Round 9: 8-phase-style counted-vmcnt GEMM (guide m201/m218 template) at
// BM=128 x BN=256 x BK=64, 512 threads (8 waves 2Mx4N), 96KB dbuf LDS.
// Per K-tile 4 phases (k-half x row-half); group-aligned staging so the
// wait is vmcnt(3) (never 0 in steady state); setprio around MFMA clusters;
// XOR-swizzled LDS via pre-swizzled global source (linear gload_lds dest).
// ---------------------------------------------------------------------------

#define ROWS 4096
#define DIM  512

typedef __bf16 bf16x8 __attribute__((ext_vector_type(8)));
typedef float  f32x4  __attribute__((ext_vector_type(4)));
typedef unsigned short u16;
typedef u16 u16x4 __attribute__((ext_vector_type(4)));
typedef u16 u16x8 __attribute__((ext_vector_type(8)));

#define RD ((size_t)ROWS * DIM)
// per-buffer u16 layout: gA0 [0,4096) | gB0 [4096,12288) | gA1 [12288,16384) | gB1 [16384,24576)
#define BUFU 24576

__device__ __forceinline__ u16 f2bf(float x) {
    union { float f; unsigned u; } c; c.f = x;
    const unsigned r = (c.u + 0x7FFFu + ((c.u >> 16) & 1u)) >> 16;
    return (u16)r;
}

__device__ __forceinline__ void gload16(const void* g, void* l) {
    __builtin_amdgcn_global_load_lds(
        (const __attribute__((address_space(1))) void*)g,
        (__attribute__((address_space(3))) void*)l, 16, 0, 0);
}

__device__ __forceinline__ float gelu_f(float v) {
    return 0.5f * v * (1.0f + erff(v * 0.70710678118654752f));
}

// ---------------- 128x256 MFMA GEMM body (512 threads) ----------------------
// C[M,N] = epi(A[M,K] @ B[N,K]^T), K tiles [ktBeg,ktEnd) in 64-k units.
// EPI: 0: f32 row-major = acc*scale | 2: bf16 = acc+bias
//      3: bf16 = gelu(acc+bias)     | 4: bf16 transposed (C[col*ldc+row])
template<int EPI>
__device__ __forceinline__ void mg_body(
    const u16* __restrict__ A, int lda,
    const u16* __restrict__ B, int ldb,
    const float* __restrict__ bias,
    void* __restrict__ C, int ldc,
    int ktBeg, int ktEnd, float scale, int m0, int n0, u16* smem)
{
    const int tid  = threadIdx.x;          // 0..511
    const int lane = tid & 63;
    const int wid  = tid >> 6;             // 0..7
    const int wm   = wid >> 2;             // 0..1 (row half, 64 rows each)
    const int wn   = wid & 3;              // 0..3 (col quarter, 64 cols each)
    const int l15  = lane & 15, kg = lane >> 4, lq = lane >> 4;

    f32x4 acc[4][4];
    #pragma unroll
    for (int i = 0; i < 4; ++i)
        #pragma unroll
        for (int j = 0; j < 4; ++j)
            acc[i][j] = (f32x4){0.f, 0.f, 0.f, 0.f};

    // ---- staging addresses (6 gload16 per thread per K-tile) ----
    // slot s in a group: row r = s>>2, stored k-slot = (s&3) ^ ((r>>1)&3)
    const int sA  = tid,        rA  = sA  >> 2, klA  = (sA  & 3) ^ ((rA  >> 1) & 3);
    const int sB0 = tid,        rB0 = sB0 >> 2, klB0 = (sB0 & 3) ^ ((rB0 >> 1) & 3);
    const int sB1 = tid + 512,  rB1 = sB1 >> 2, klB1 = (sB1 & 3) ^ ((rB1 >> 1) & 3);
    const u16* gA  = A + (size_t)(m0 + rA)  * lda + (klA  << 3) + (size_t)ktBeg * 64;
    const u16* gB0 = B + (size_t)(n0 + rB0) * ldb + (klB0 << 3) + (size_t)ktBeg * 64;
    const u16* gB1 = B + (size_t)(n0 + rB1) * ldb + (klB1 << 3) + (size_t)ktBeg * 64;
    const int dA0 = sA << 3;
    const int dB0a = 4096  + (sB0 << 3), dB0b = 4096  + (sB1 << 3);
    const int dA1 = 12288 + (sA << 3);
    const int dB1a = 16384 + (sB0 << 3), dB1b = 16384 + (sB1 << 3);

    // ---- fragment ds_read offsets (u16, within buffer) ----
    int aoff[2][4], boff[2][4];
    #pragma unroll
    for (int ks = 0; ks < 2; ++ks) {
        #pragma unroll
        for (int ri = 0; ri < 4; ++ri) {
            const int r = wm * 64 + ri * 16 + l15;
            aoff[ks][ri] = (ks ? 12288 : 0) + ((r << 2) + (kg ^ ((r >> 1) & 3)) << 3);
        }
        #pragma unroll
        for (int cj = 0; cj < 4; ++cj) {
            const int r = wn * 64 + cj * 16 + l15;
            boff[ks][cj] = (ks ? 16384 : 4096) + ((r << 2) + (kg ^ ((r >> 1) & 3)) << 3);
        }
    }

    const int nt = ktEnd - ktBeg;

    if (nt > 0) {
        // prologue: stage tile 0 into buf0 (order: A0, B0x2, A1, B1x2)
        {
            u16* bb = smem;
            gload16(gA,       bb + dA0);
            gload16(gB0,      bb + dB0a);
            gload16(gB1,      bb + dB0b);
            gload16(gA + 32,  bb + dA1);
            gload16(gB0 + 32, bb + dB1a);
            gload16(gB1 + 32, bb + dB1b);
        }
        for (int t = 0; t < nt; ++t) {
            const u16* bc = smem + (t & 1) * BUFU;
            u16* bn = smem + ((t + 1) & 1) * BUFU;
            const bool more = (t + 1 < nt);
            const int ko = (t + 1) << 6;     // u16 k-advance for next tile

            bf16x8 a0, a1, b_[4];

            // ---- phase 0: ks=0, acc rows 0,1 ----
            asm volatile("s_waitcnt vmcnt(3)" ::: "memory");  // A0,B0 of tile t landed
            __builtin_amdgcn_s_barrier();
            asm volatile("" ::: "memory");
            a0 = *reinterpret_cast<const bf16x8*>(&bc[aoff[0][0]]);
            a1 = *reinterpret_cast<const bf16x8*>(&bc[aoff[0][1]]);
            #pragma unroll
            for (int j = 0; j < 4; ++j)
                b_[j] = *reinterpret_cast<const bf16x8*>(&bc[boff[0][j]]);
            if (more) gload16(gA + ko, bn + dA0);
            __builtin_amdgcn_s_setprio(1);
            #pragma unroll
            for (int j = 0; j < 4; ++j) {
                if (EPI == 4) {
                    acc[0][j] = __builtin_amdgcn_mfma_f32_16x16x32_bf16(a0, b_[j], acc[0][j], 0, 0, 0);
                    acc[1][j] = __builtin_amdgcn_mfma_f32_16x16x32_bf16(a1, b_[j], acc[1][j], 0, 0, 0);
                } else {
                    acc[0][j] = __builtin_amdgcn_mfma_f32_16x16x32_bf16(b_[j], a0, acc[0][j], 0, 0, 0);
                    acc[1][j] = __builtin_amdgcn_mfma_f32_16x16x32_bf16(b_[j], a1, acc[1][j], 0, 0, 0);
                }
            }
            __builtin_amdgcn_s_setprio(0);

            // ---- phase 1: ks=0, acc rows 2,3 (reuse b_) ----
            __builtin_amdgcn_s_barrier();
            asm volatile("" ::: "memory");
            a0 = *reinterpret_cast<const bf16x8*>(&bc[aoff[0][2]]);
            a1 = *reinterpret_cast<const bf16x8*>(&bc[aoff[0][3]]);
            if (more) { gload16(gB0 + ko, bn + dB0a); gload16(gB1 + ko, bn + dB0b); }
            __builtin_amdgcn_s_setprio(1);
            #pragma unroll
            for (int j = 0; j < 4; ++j) {
                if (EPI == 4) {
                    acc[2][j] = __builtin_amdgcn_mfma_f32_16x16x32_bf16(a0, b_[j], acc[2][j], 0, 0, 0);
                    acc[3][j] = __builtin_amdgcn_mfma_f32_16x16x32_bf16(a1, b_[j], acc[3][j], 0, 0, 0);
                } else {
                    acc[2][j] = __builtin_amdgcn_mfma_f32_16x16x32_bf16(b_[j], a0, acc[2][j], 0, 0, 0);
                    acc[3][j] = __builtin_amdgcn_mfma_f32_16x16x32_bf16(b_[j], a1, acc[3][j], 0, 0, 0);
                }
            }
            __builtin_amdgcn_s_setprio(0);

            // ---- phase 2: ks=1, acc rows 0,1 ----
            if (more) asm volatile("s_waitcnt vmcnt(3)" ::: "memory");  // A1,B1 of t landed
            else      asm volatile("s_waitcnt vmcnt(0)" ::: "memory");
            __builtin_amdgcn_s_barrier();
            asm volatile("" ::: "memory");
            a0 = *reinterpret_cast<const bf16x8*>(&bc[aoff[1][0]]);
            a1 = *reinterpret_cast<const bf16x8*>(&bc[aoff[1][1]]);
            #pragma unroll
            for (int j = 0; j < 4; ++j)
                b_[j] = *reinterpret_cast<const bf16x8*>(&bc[boff[1][j]]);
            if (more) gload16(gA + ko + 32, bn + dA1);
            __builtin_amdgcn_s_setprio(1);
            #pragma unroll
            for (int j = 0; j < 4; ++j) {
                if (EPI == 4) {
                    acc[0][j] = __builtin_amdgcn_mfma_f32_16x16x32_bf16(a0, b_[j], acc[0][j], 0, 0, 0);
                    acc[1][j] = __builtin_amdgcn_mfma_f32_16x16x32_bf16(a1, b_[j], acc[1][j], 0, 0, 0);
                } else {
                    acc[0][j] = __builtin_amdgcn_mfma_f32_16x16x32_bf16(b_[j], a0, acc[0][j], 0, 0, 0);
                    acc[1][j] = __builtin_amdgcn_mfma_f32_16x16x32_bf16(b_[j], a1, acc[1][j], 0, 0, 0);
                }
            }
            __builtin_amdgcn_s_setprio(0);

            // ---- phase 3: ks=1, acc rows 2,3 (reuse b_) ----
            __builtin_amdgcn_s_barrier();
            asm volatile("" ::: "memory");
            a0 = *reinterpret_cast<const bf16x8*>(&bc[aoff[1][2]]);
            a1 = *reinterpret_cast<const bf16x8*>(&bc[aoff[1][3]]);
            if (more) { gload16(gB0 + ko + 32, bn + dB1a); gload16(gB1 + ko + 32, bn + dB1b); }
            __builtin_amdgcn_s_setprio(1);
            #pragma unroll
            for (int j = 0; j < 4; ++j) {
                if (EPI == 4) {
                    acc[2][j] = __builtin_amdgcn_mfma_f32_16x16x32_bf16(a0, b_[j], acc[2][j], 0, 0, 0);
                    acc[3][j] = __builtin_amdgcn_mfma_f32_16x16x32_bf16(a1, b_[j], acc[3][j], 0, 0, 0);
                } else {
                    acc[2][j] = __builtin_amdgcn_mfma_f32_16x16x32_bf16(b_[j], a0, acc[2][j], 0, 0, 0);
                    acc[3][j] = __builtin_amdgcn_mfma_f32_16x16x32_bf16(b_[j], a1, acc[3][j], 0, 0, 0);
                }
            }
            __builtin_amdgcn_s_setprio(0);
        }
    }

    // ---- epilogue ----
    if (EPI == 4) {
        // unswapped: D[m = lq*4+reg][n = l15]; store u16x4 down token dim of vT
        #pragma unroll
        for (int j = 0; j < 4; ++j) {
            const int col = n0 + wn * 64 + (j << 4) + l15;
            const float bj = bias[col];
            #pragma unroll
            for (int i = 0; i < 4; ++i) {
                const int row0 = m0 + wm * 64 + (i << 4) + (lq << 2);
                u16x4 pk;
                #pragma unroll
                for (int r = 0; r < 4; ++r) pk[r] = f2bf(acc[i][j][r] + bj);
                *reinterpret_cast<u16x4*>(&((u16*)C)[(size_t)col * ldc + row0]) = pk;
            }
        }
    } else {
        // swapped: D[n = lq*4+reg][m = l15] -> reg walks C columns (row-major)
        #pragma unroll
        for (int j = 0; j < 4; ++j) {
            const int col0 = n0 + wn * 64 + (j << 4) + (lq << 2);
            float4 bj = {0.f, 0.f, 0.f, 0.f};
            if (EPI != 0) bj = *reinterpret_cast<const float4*>(&bias[col0]);
            #pragma unroll
            for (int i = 0; i < 4; ++i) {
                const int row = m0 + wm * 64 + (i << 4) + l15;
                f32x4 v = acc[i][j];
                if (EPI == 0) {
                    v[0] *= scale; v[1] *= scale; v[2] *= scale; v[3] *= scale;
                    *reinterpret_cast<f32x4*>(&((float*)C)[(size_t)row * ldc + col0]) = v;
                } else {
                    v[0] += bj.x; v[1] += bj.y; v[2] += bj.z; v[3] += bj.w;
                    if (EPI == 3) {
                        v[0] = gelu_f(v[0]); v[1] = gelu_f(v[1]);
                        v[2] = gelu_f(v[2]); v[3] = gelu_f(v[3]);
                    }
                    u16x4 pk = {f2bf(v[0]), f2bf(v[1]), f2bf(v[2]), f2bf(v[3])};
                    *reinterpret_cast<u16x4*>(&((u16*)C)[(size_t)row * ldc + col0]) = pk;
                }
            }
        }
    }
}

// ---------------- GEMM kernels ----------------------------------------------
__global__ __launch_bounds__(512, 2) void g_qkv(
    const u16* __restrict__ xa, const u16* __restrict__ cfb,
    const u16* __restrict__ Wqb, const u16* __restrict__ Wkb,
    const u16* __restrict__ Wvb,
    const float* __restrict__ bq, const float* __restrict__ bk,
    const float* __restrict__ bv,
    u16* __restrict__ q, u16* __restrict__ k, u16* __restrict__ vT)
{
    __shared__ u16 smem[2 * BUFU];
    const int m0 = blockIdx.x << 7;
    const int which = blockIdx.y >> 1;
    const int n0 = (blockIdx.y & 1) << 8;
    if (which == 0)
        mg_body<2>(xa,  512, Wqb, 512, bq, q,  512,  0, 8, 1.f, m0, n0, smem);
    else if (which == 1)
        mg_body<2>(cfb, 512, Wkb, 512, bk, k,  512,  0, 8, 1.f, m0, n0, smem);
    else
        mg_body<4>(cfb, 512, Wvb, 512, bv, vT, 4096, 0, 8, 1.f, m0, n0, smem);
}

// block-causal scores: 128-row x 256-col tiles, live iff nt <= mt>>1.
__device__ __forceinline__ int tri_pref(int b) {
    const int h = b >> 1;
    return (b & 1) ? (h + 1) * (h + 1) : h * (h + 1);
}
__global__ __launch_bounds__(512, 2) void g_tri(
    const u16* __restrict__ qb, const u16* __restrict__ kb,
    float* __restrict__ S, float scale)
{
    const int z = blockIdx.x;
    int mt = 2 * (int)sqrtf((float)z);
    while (tri_pref(mt + 1) <= z) ++mt;
    while (tri_pref(mt) > z) --mt;
    const int nt = z - tri_pref(mt);
    __shared__ u16 smem[2 * BUFU];
    mg_body<0>(qb, 512, kb, 512, nullptr, S, 4096, 0, 8, scale, mt << 7, nt << 8, smem);
}

// AV split-K: k-tile bound = 2*mt+2 (P zero-padded to 128-aligned edge).
__global__ __launch_bounds__(512, 2) void g_av(
    const u16* __restrict__ P, const u16* __restrict__ vT,
    float* __restrict__ part)
{
    const int mt = blockIdx.x, n0 = blockIdx.y << 8, z = blockIdx.z;
    const int kts = 2 * mt + 2;
    const int ch = (kts + 3) >> 2;
    int kb = z * ch; if (kb > kts) kb = kts;
    int ke = kb + ch; if (ke > kts) ke = kts;
    __shared__ u16 smem[2 * BUFU];
    mg_body<0>(P, 4096, vT, 4096, nullptr, part + (size_t)z * RD, 512,
               kb, ke, 1.f, mt << 7, n0, smem);
}

__global__ __launch_bounds__(512, 2) void g_mlp1(
    const u16* __restrict__ xb, const u16* __restrict__ W1b,
    const float* __restrict__ b1, u16* __restrict__ h)
{
    __shared__ u16 smem[2 * BUFU];
    mg_body<3>(xb, 512, W1b, 512, b1, h, 2048, 0, 8, 1.f,
               blockIdx.x << 7, blockIdx.y << 8, smem);
}

__global__ __launch_bounds__(512, 2) void g_mlp2(
    const u16* __restrict__ h, const u16* __restrict__ W2b,
    float* __restrict__ part)
{
    const int z = blockIdx.z;
    __shared__ u16 smem[2 * BUFU];
    mg_body<0>(h, 2048, W2b, 2048, nullptr, part + (size_t)z * RD, 512,
               z * 8, z * 8 + 8, 1.f, blockIdx.x << 7, blockIdx.y << 8, smem);
}

__global__ __launch_bounds__(512, 2) void g_gate(
    const u16* __restrict__ cat, const u16* __restrict__ Wsb,
    float* __restrict__ part)
{
    const int z = blockIdx.z;
    __shared__ u16 smem[2 * BUFU];
    mg_body<0>(cat, 1024, Wsb, 1024, nullptr, part + (size_t)z * RD, 512,
               z * 8, z * 8 + 8, 1.f, blockIdx.x << 7, blockIdx.y << 8, smem);
}

// ------- masked row softmax (2 passes): p = exp(s - max) bf16 (UNNORMALIZED),
//         sums[row] = denom; zero-pads p to the 128-aligned edge.
__global__ __launch_bounds__(256) void softmax_pbf(
    const float* __restrict__ S, u16* __restrict__ P, float* __restrict__ sums)
{
    const int row = blockIdx.x;
    const int b   = row >> 5;
    const int Lb  = b << 5;
    const int bound = ((row >> 7) + 1) << 7;
    const float* s = S + (size_t)row * 4096;
    u16* p = P + (size_t)row * 4096;
    const int tid = threadIdx.x;

    const u16x8 z8 = {0, 0, 0, 0, 0, 0, 0, 0};
    for (int m = Lb + tid * 8; m < bound; m += 2048)
        *reinterpret_cast<u16x8*>(&p[m]) = z8;
    if (b == 0) { if (tid == 0) sums[row] = 1.f; return; }

    __shared__ float red[4];
    float mx = -3.0e38f;
    for (int m = tid * 4; m < Lb; m += 1024) {
        const float4 v = *reinterpret_cast<const float4*>(&s[m]);
        mx = fmaxf(mx, fmaxf(fmaxf(v.x, v.y), fmaxf(v.z, v.w)));
    }
    #pragma unroll
    for (int off = 32; off; off >>= 1) mx = fmaxf(mx, __shfl_xor(mx, off));
    if ((tid & 63) == 0) red[tid >> 6] = mx;
    __syncthreads();
    mx = fmaxf(fmaxf(red[0], red[1]), fmaxf(red[2], red[3]));
    __syncthreads();

    float sum = 0.f;
    for (int m = tid * 8; m < Lb; m += 2048) {
        const float4 v0 = *reinterpret_cast<const float4*>(&s[m]);
        const float4 v1 = *reinterpret_cast<const float4*>(&s[m + 4]);
        float e[8];
        e[0] = expf(v0.x - mx); e[1] = expf(v0.y - mx);
        e[2] = expf(v0.z - mx); e[3] = expf(v0.w - mx);
        e[4] = expf(v1.x - mx); e[5] = expf(v1.y - mx);
        e[6] = expf(v1.z - mx); e[7] = expf(v1.w - mx);
        u16x8 o;
        #pragma unroll
        for (int i = 0; i < 8; ++i) { sum += e[i]; o[i] = f2bf(e[i]); }
        *reinterpret_cast<u16x8*>(&p[m]) = o;
    }
    #pragma unroll
    for (int off = 32; off; off >>= 1) sum += __shfl_xor(sum, off);
    if ((tid & 63) == 0) red[tid >> 6] = sum;
    __syncthreads();
    if (tid == 0)
        sums[row] = fmaxf(red[0] + red[1] + red[2] + red[3], 1e-30f);
}

// --- x = LN(xin + (sum_s part[s]) * (DIV? 1/sums[row] : 1) (+bias)) ---------
template<int NS, bool HASB, bool DIV>
__global__ __launch_bounds__(256) void ln_res_ps(
    const float* __restrict__ Xin, const float* __restrict__ part,
    const float* __restrict__ bias, const float* __restrict__ sums,
    const float* __restrict__ gamma, const float* __restrict__ beta,
    float* __restrict__ Xout, u16* __restrict__ Xbf)
{
    const int row  = blockIdx.x * 4 + (threadIdx.x >> 6);
    const int lane = threadIdx.x & 63;
    const float* xr = Xin + (size_t)row * DIM;
    const int d0 = lane << 3;
    const float inv = DIV ? (1.0f / sums[row]) : 1.0f;

    const float4 x0 = *reinterpret_cast<const float4*>(&xr[d0]);
    const float4 x1 = *reinterpret_cast<const float4*>(&xr[d0 + 4]);
    float a[8] = {0.f, 0.f, 0.f, 0.f, 0.f, 0.f, 0.f, 0.f};
    #pragma unroll
    for (int s = 0; s < NS; ++s) {
        const float* pr = part + (size_t)s * RD + (size_t)row * DIM + d0;
        const float4 p0 = *reinterpret_cast<const float4*>(pr);
        const float4 p1 = *reinterpret_cast<const float4*>(pr + 4);
        a[0] += p0.x; a[1] += p0.y; a[2] += p0.z; a[3] += p0.w;
        a[4] += p1.x; a[5] += p1.y; a[6] += p1.z; a[7] += p1.w;
    }
    float v[8] = {x0.x, x0.y, x0.z, x0.w, x1.x, x1.y, x1.z, x1.w};
    #pragma unroll
    for (int i = 0; i < 8; ++i) v[i] += a[i] * inv;
    if (HASB) {
        const float4 b0 = *reinterpret_cast<const float4*>(&bias[d0]);
        const float4 b1 = *reinterpret_cast<const float4*>(&bias[d0 + 4]);
        v[0] += b0.x; v[1] += b0.y; v[2] += b0.z; v[3] += b0.w;
        v[4] += b1.x; v[5] += b1.y; v[6] += b1.z; v[7] += b1.w;
    }

    float sm = 0.f;
    #pragma unroll
    for (int i = 0; i < 8; ++i) sm += v[i];
    #pragma unroll
    for (int off = 32; off; off >>= 1) sm += __shfl_xor(sm, off);
    const float mu = sm * (1.0f / 512.0f);

    float qs = 0.f;
    #pragma unroll
    for (int i = 0; i < 8; ++i) { const float d = v[i] - mu; qs += d * d; }
    #pragma unroll
    for (int off = 32; off; off >>= 1) qs += __shfl_xor(qs, off);
    const float rs = rsqrtf(qs * (1.0f / 512.0f) + 1e-5f);

    const float4 g0 = *reinterpret_cast<const float4*>(&gamma[d0]);
    const float4 g1 = *reinterpret_cast<const float4*>(&gamma[d0 + 4]);
    const float4 b0 = *reinterpret_cast<const float4*>(&beta[d0]);
    const float4 b1 = *reinterpret_cast<const float4*>(&beta[d0 + 4]);
    float o[8];
    o[0] = (v[0] - mu) * rs * g0.x + b0.x;
    o[1] = (v[1] - mu) * rs * g0.y + b0.y;
    o[2] = (v[2] - mu) * rs * g0.z + b0.z;
    o[3] = (v[3] - mu) * rs * g0.w + b0.w;
    o[4] = (v[4] - mu) * rs * g1.x + b1.x;
    o[5] = (v[5] - mu) * rs * g1.y + b1.y;
    o[6] = (v[6] - mu) * rs * g1.z + b1.z;
    o[7] = (v[7] - mu) * rs * g1.w + b1.w;

    float4 f0 = {o[0], o[1], o[2], o[3]}, f1 = {o[4], o[5], o[6], o[7]};
    *reinterpret_cast<float4*>(&Xout[(size_t)row * DIM + d0])     = f0;
    *reinterpret_cast<float4*>(&Xout[(size_t)row * DIM + d0 + 4]) = f1;
    u16x8 ob;
    #pragma unroll
    for (int i = 0; i < 8; ++i) ob[i] = f2bf(o[i]);
    *reinterpret_cast<u16x8*>(&Xbf[(size_t)row * DIM + d0]) = ob;
}

// ---------------- fused f32->bf16 conversion for 7 arrays -------------------
struct ConvArgs {
    const float* src[7];
    u16* dst[7];
    int start[8];
};

__global__ __launch_bounds__(256) void conv_all(ConvArgs a)
{
    const int b = blockIdx.x;
    int seg = 0;
    #pragma unroll
    for (int i = 1; i < 7; ++i) seg += (a.start[i] <= b) ? 1 : 0;
    const int i = ((b - a.start[seg]) * 256 + threadIdx.x) << 3;
    const float* s = a.src[seg];
    const float4 lo = *reinterpret_cast<const float4*>(&s[i]);
    const float4 hi = *reinterpret_cast<const float4*>(&s[i + 4]);
    u16x8 o = {f2bf(lo.x), f2bf(lo.y), f2bf(lo.z), f2bf(lo.w),
               f2bf(hi.x), f2bf(hi.y), f2bf(hi.z), f2bf(hi.w)};
    *reinterpret_cast<u16x8*>(&a.dst[seg][i]) = o;
}

// ---------------- small helpers ---------------------------------------------
__global__ __launch_bounds__(256) void build_cat(
    u16* __restrict__ cat, const u16* __restrict__ cfb, const u16* __restrict__ xbf)
{
    const int idx = blockIdx.x * 256 + threadIdx.x;
    const int row = idx >> 7;
    const int c8  = idx & 127;
    const u16* src2 = (row < 32) ? cfb : xbf;
    const u16x8 v = (c8 < 64)
        ? *reinterpret_cast<const u16x8*>(&cfb[(size_t)row * 512 + (c8 << 3)])
        : *reinterpret_cast<const u16x8*>(&src2[(size_t)row * 512 + ((c8 - 64) << 3)]);
    *reinterpret_cast<u16x8*>(&cat[(size_t)row * 1024 + (c8 << 3)]) = v;
}

__global__ __launch_bounds__(256) void final_gate_ps(
    float4* __restrict__ out, const float4* __restrict__ cf,
    const float4* __restrict__ x, const float* __restrict__ part,
    const float* __restrict__ bias)
{
    const int idx = blockIdx.x * 256 + threadIdx.x;
    const int row = idx >> 7;
    const int c4  = idx & 127;
    const float4 zc = cf[idx];
    const float4 p0 = reinterpret_cast<const float4*>(part)[idx];
    const float4 p1 = reinterpret_cast<const float4*>(part + RD)[idx];
    const float4 bb = *reinterpret_cast<const float4*>(&bias[c4 << 2]);
    const float4 za = (row < 32) ? zc : x[idx];
    float4 o;
    { const float g = 1.0f / (1.0f + expf(-(p0.x + p1.x + bb.x))); o.x = g * zc.x + (1.0f - g) * za.x; }
    { const float g = 1.0f / (1.0f + expf(-(p0.y + p1.y + bb.y))); o.y = g * zc.y + (1.0f - g) * za.y; }
    { const float g = 1.0f / (1.0f + expf(-(p0.z + p1.z + bb.z))); o.z = g * zc.z + (1.0f - g) * za.z; }
    { const float g = 1.0f / (1.0f + expf(-(p0.w + p1.w + bb.w))); o.w = g * zc.w + (1.0f - g) * za.w; }
    out[idx] = o;
}

// ---------------------------------------------------------------------------
extern "C" void kernel_launch(void* const* d_in, const int* in_sizes, int n_in,
                              void* d_out, int out_size, void* d_ws, size_t ws_size,
                              hipStream_t stream)
{
    const float* cf   = (const float*)d_in[0];
    const float* Wq   = (const float*)d_in[1];
    const float* bq   = (const float*)d_in[2];
    const float* Wk   = (const float*)d_in[3];
    const float* bk   = (const float*)d_in[4];
    const float* Wv   = (const float*)d_in[5];
    const float* bv   = (const float*)d_in[6];
    const float* ln1g = (const float*)d_in[7];
    const float* ln1b = (const float*)d_in[8];
    const float* W1   = (const float*)d_in[9];
    const float* b1   = (const float*)d_in[10];
    const float* W2   = (const float*)d_in[11];
    const float* b2   = (const float*)d_in[12];
    const float* ln2g = (const float*)d_in[13];
    const float* ln2b = (const float*)d_in[14];
    const float* Wsg  = (const float*)d_in[15];
    const float* bsg  = (const float*)d_in[16];
    float* out = (float*)d_out;

    float* ws   = (float*)d_ws;
    float* x    = ws;                               // [4096,512] f32
    float* sums = ws + RD;                          // [4096] f32
    float* s    = ws + 2 * RD;                      // [4096,4096] f32 (attn)
    float* part = ws + 2 * RD;                      // 4x[4096,512] f32 partials
    u16*  pbf  = (u16*)(ws + 10 * RD);              // P [4096,4096] bf16
    u16*  hbf  = (u16*)(ws + 10 * RD);              // h [4096,2048] bf16 (alias)
    u16*  catb = (u16*)(ws + 10 * RD);              // cat [4096,1024] bf16 (alias)
    u16*  bfb  = (u16*)(ws + 14 * RD);
    u16* cfb = bfb;
    u16* xbf = bfb + RD;
    u16* qbf = bfb + 2 * RD;
    u16* kbf = bfb + 3 * RD;
    u16* vTb = bfb + 4 * RD;                        // [512,4096] (V transposed)
    u16* Wqb = bfb + 5 * RD;
    u16* Wkb = Wqb + 524288;
    u16* Wvb = Wkb + 524288;
    u16* W1b = Wvb + 524288;
    u16* W2b = W1b + 2097152;
    u16* Wsb = W2b + 2097152;

    const float scale = 0.044194173824159216f;      // 1/sqrt(512)

    ConvArgs ca;
    ca.src[0] = cf;  ca.dst[0] = cfb;
    ca.src[1] = Wq;  ca.dst[1] = Wqb;
    ca.src[2] = Wk;  ca.dst[2] = Wkb;
    ca.src[3] = Wv;  ca.dst[3] = Wvb;
    ca.src[4] = W1;  ca.dst[4] = W1b;
    ca.src[5] = W2;  ca.dst[5] = W2b;
    ca.src[6] = Wsg; ca.dst[6] = Wsb;
    ca.start[0] = 0;    ca.start[1] = 1024; ca.start[2] = 1280;
    ca.start[3] = 1536; ca.start[4] = 1792; ca.start[5] = 2816;
    ca.start[6] = 3840; ca.start[7] = 4096;
    conv_all<<<4096, 256, 0, stream>>>(ca);

    for (int l = 0; l < 2; ++l) {
        const u16* xa = (l == 0) ? cfb : xbf;
        g_qkv<<<dim3(32, 6), 512, 0, stream>>>(
            xa, cfb, Wqb + l * 262144, Wkb + l * 262144, Wvb + l * 262144,
            bq + l * 512, bk + l * 512, bv + l * 512, qbf, kbf, vTb);
        g_tri<<<272, 512, 0, stream>>>(qbf, kbf, s, scale);
        softmax_pbf<<<4096, 256, 0, stream>>>(s, pbf, sums);
        g_av<<<dim3(32, 2, 4), 512, 0, stream>>>(pbf, vTb, part);
        ln_res_ps<4, false, true><<<1024, 256, 0, stream>>>(
            (l == 0) ? cf : x, part, nullptr, sums,
            ln1g + l * 512, ln1b + l * 512, x, xbf);
        g_mlp1<<<dim3(32, 8), 512, 0, stream>>>(
            xbf, W1b + l * 1048576, b1 + l * 2048, hbf);
        g_mlp2<<<dim3(32, 2, 4), 512, 0, stream>>>(hbf, W2b + l * 1048576, part);
        ln_res_ps<4, true, false><<<1024, 256, 0, stream>>>(
            x, part, b2 + l * 512, nullptr,
            ln2g + l * 512, ln2b + l * 512, x, xbf);
    }

    build_cat<<<2048, 256, 0, stream>>>(catb, cfb, xbf);
    g_gate<<<dim3(32, 2, 2), 512, 0, stream>>>(catb, Wsb, part);
    final_gate_ps<<<2048, 256, 0, stream>>>((float4*)out, (const float4*)cf,
                                            (const float4*)x, part, bsg);
}